// Round 6
// baseline (276.810 us; speedup 1.0000x reference)
//
#include <hip/hip_runtime.h>
#include <hip/hip_bf16.h>

#define GAS __attribute__((address_space(1)))
#define LAS __attribute__((address_space(3)))

typedef __attribute__((ext_vector_type(8))) short bf16x8;
typedef __attribute__((ext_vector_type(4))) float f32x4;

#define D_MODEL 1024
#define NHEADS 16
#define DK 64
#define BB 4
#define SS 2048

#define SM_SCALE 0.18033688011112042f  /* 1/sqrt(64) * log2(e), folded into Q at RoPE */

static __device__ __forceinline__ float b2f(unsigned short u) {
  union { unsigned int i; float f; } c; c.i = ((unsigned int)u) << 16; return c.f;
}
static __device__ __forceinline__ unsigned short f2b(float f) {
  union { float f; unsigned int i; } c; c.f = f;
  unsigned int x = c.i;
  x += 0x7fffu + ((x >> 16) & 1u);   // RNE
  return (unsigned short)(x >> 16);
}
// pack 2 f32 -> 2 bf16 (RNE) in one instruction
static __device__ __forceinline__ unsigned int cvtpk(float lo, float hi) {
  unsigned int r;
  asm("v_cvt_pk_bf16_f32 %0, %1, %2" : "=v"(r) : "v"(lo), "v"(hi));
  return r;
}
// raw 2^x (hardware v_exp_f32)
static __device__ __forceinline__ float fexp2(float x) {
  float r;
  asm("v_exp_f32 %0, %1" : "=v"(r) : "v"(x));
  return r;
}

// ---------------- cast f32 -> bf16 (vectorized float4 -> ushort4) ----------
__global__ __launch_bounds__(256) void cast_kernel(const float* __restrict__ in,
                                                   unsigned short* __restrict__ out,
                                                   int n4) {
  int i = blockIdx.x * 256 + threadIdx.x;
  if (i >= n4) return;
  float4 v = reinterpret_cast<const float4*>(in)[i];
  ushort4 o;
  o.x = f2b(v.x); o.y = f2b(v.y); o.z = f2b(v.z); o.w = f2b(v.w);
  reinterpret_cast<ushort4*>(out)[i] = o;
}

// all 4 weight matrices in one launch; dst regions are contiguous in ws
__global__ __launch_bounds__(256) void cast4_kernel(const float* __restrict__ a,
                                                    const float* __restrict__ b,
                                                    const float* __restrict__ c,
                                                    const float* __restrict__ d,
                                                    unsigned short* __restrict__ out) {
  int i = blockIdx.x * 256 + threadIdx.x;  // < 4 * 262144
  int which = i >> 18, off = i & 0x3ffff;
  const float* src = which == 0 ? a : which == 1 ? b : which == 2 ? c : d;
  float4 v = reinterpret_cast<const float4*>(src)[off];
  ushort4 o;
  o.x = f2b(v.x); o.y = f2b(v.y); o.z = f2b(v.z); o.w = f2b(v.w);
  reinterpret_cast<ushort4*>(out)[i] = o;
}

// ---------------- bf16 GEMM, C = A (M x K) * B^T (N x K), K = 1024 --------
static __device__ __forceinline__ void gl_lds16(const void* g, void* l) {
  __builtin_amdgcn_global_load_lds((const GAS unsigned int*)g,
                                   (LAS unsigned int*)l, 16, 0, 0);
}

template <int EPI>
__global__ __launch_bounds__(256) void gemm_bt(const unsigned short* __restrict__ A,
                                               const unsigned short* __restrict__ Bw,
                                               void* __restrict__ outp, int N) {
  const int K = 1024;
  __shared__ unsigned short lds_a[128 * 32];
  __shared__ unsigned short lds_b[128 * 32];
  int t = threadIdx.x;
  int lane = t & 63;
  int w = t >> 6, wr = w >> 1, wc = w & 1;
  int la = lane & 15, lg = lane >> 4;
  int rowBase = blockIdx.x * 128;
  int colBase = blockIdx.y * 128;
  const unsigned short* Ab = A + (size_t)(rowBase + (t >> 2)) * K + (t & 3) * 8;
  const unsigned short* Bb = Bw + (size_t)(colBase + (t >> 2)) * K + (t & 3) * 8;

  f32x4 acc[4][4];
#pragma unroll
  for (int i = 0; i < 4; ++i)
#pragma unroll
    for (int j = 0; j < 4; ++j) acc[i][j] = (f32x4){0.f, 0.f, 0.f, 0.f};

  for (int k0 = 0; k0 < K; k0 += 32) {
    gl_lds16(Ab + k0, &lds_a[t * 8]);
    gl_lds16(Ab + (size_t)64 * K + k0, &lds_a[2048 + t * 8]);
    gl_lds16(Bb + k0, &lds_b[t * 8]);
    gl_lds16(Bb + (size_t)64 * K + k0, &lds_b[2048 + t * 8]);
    __syncthreads();
    bf16x8 af[4], bfr[4];
#pragma unroll
    for (int mi = 0; mi < 4; ++mi)
      af[mi] = *reinterpret_cast<const bf16x8*>(&lds_a[(wr * 64 + mi * 16 + la) * 32 + lg * 8]);
#pragma unroll
    for (int ni = 0; ni < 4; ++ni)
      bfr[ni] = *reinterpret_cast<const bf16x8*>(&lds_b[(wc * 64 + ni * 16 + la) * 32 + lg * 8]);
#pragma unroll
    for (int mi = 0; mi < 4; ++mi)
#pragma unroll
      for (int ni = 0; ni < 4; ++ni)
        acc[mi][ni] = __builtin_amdgcn_mfma_f32_16x16x32_bf16(af[mi], bfr[ni], acc[mi][ni], 0, 0, 0);
    __syncthreads();
  }

  if (EPI == 0) {
    float* out = (float*)outp;
#pragma unroll
    for (int mi = 0; mi < 4; ++mi)
#pragma unroll
      for (int ni = 0; ni < 4; ++ni)
#pragma unroll
        for (int j = 0; j < 4; ++j) {
          int row = rowBase + wr * 64 + mi * 16 + lg * 4 + j;
          int col = colBase + wc * 64 + ni * 16 + la;
          out[(size_t)row * N + col] = acc[mi][ni][j];
        }
  } else {
    // Q,K: [which][b,h,s,d].  V: transposed [b,h,d,s].
    unsigned short* qkv = (unsigned short*)outp;
#pragma unroll
    for (int mi = 0; mi < 4; ++mi)
#pragma unroll
      for (int ni = 0; ni < 4; ++ni)
#pragma unroll
        for (int j = 0; j < 4; ++j) {
          int row = rowBase + wr * 64 + mi * 16 + lg * 4 + j;
          int col = colBase + wc * 64 + ni * 16 + la;
          int which = col >> 10, d = col & 1023;
          int h = d >> 6, dd = d & 63;
          int b = row >> 11, s = row & 2047;
          size_t off;
          if (which == 2)
            off = (size_t)2 * 8388608 +
                  ((size_t)(b * NHEADS + h) * DK + dd) * SS + s;
          else
            off = (size_t)which * 8388608 +
                  ((size_t)(b * NHEADS + h) * SS + s) * DK + dd;
          qkv[off] = f2b(acc[mi][ni][j]);
        }
  }
}

// ---------------- RoPE: trig table + vectorized apply ----------------------
__global__ __launch_bounds__(256) void rope_table_kernel(const int* __restrict__ pos,
                                                         float2* __restrict__ ctab) {
  int i = blockIdx.x * 256 + threadIdx.x;  // 2048 * 32
  int s = i >> 5, pr = i & 31;
  float p = (float)pos[s];
  float ang = p * __expf(-(float)pr * 0.2878231366242557f);  // ln(1e4)/32
  float sn, cs;
  sincosf(ang, &sn, &cs);
  ctab[i] = make_float2(cs, sn);
}

// each thread: 4 pairs (16B). Q rows scaled by SM_SCALE.
__global__ __launch_bounds__(256) void rope_kernel(unsigned short* __restrict__ Q,
                                                   unsigned short* __restrict__ Kk,
                                                   const float2* __restrict__ ctab) {
  int i = blockIdx.x * 256 + threadIdx.x;  // < 2 * 64*2048*8 = 2097152
  int seg = i & 7;
  int row = (i >> 3) & 131071;  // bh*2048 + s
  int isK = i >> 20;
  unsigned short* base = isK ? Kk : Q;
  int s = row & 2047;
  float sc = isK ? 1.0f : SM_SCALE;
  const float4* ct4 = reinterpret_cast<const float4*>(ctab + s * 32 + seg * 4);
  float4 ca = ct4[0], cb = ct4[1];  // (c0,s0,c1,s1), (c2,s2,c3,s3)
  unsigned int* pp = reinterpret_cast<unsigned int*>(base + (size_t)row * 64 + seg * 8);
  uint4 v = *reinterpret_cast<uint4*>(pp);
  uint4 r;
  {
    float x1 = b2f((unsigned short)(v.x & 0xffffu)), x2 = b2f((unsigned short)(v.x >> 16));
    r.x = cvtpk((x1 * ca.x - x2 * ca.y) * sc, (x1 * ca.y + x2 * ca.x) * sc);
    x1 = b2f((unsigned short)(v.y & 0xffffu)); x2 = b2f((unsigned short)(v.y >> 16));
    r.y = cvtpk((x1 * ca.z - x2 * ca.w) * sc, (x1 * ca.w + x2 * ca.z) * sc);
    x1 = b2f((unsigned short)(v.z & 0xffffu)); x2 = b2f((unsigned short)(v.z >> 16));
    r.z = cvtpk((x1 * cb.x - x2 * cb.y) * sc, (x1 * cb.y + x2 * cb.x) * sc);
    x1 = b2f((unsigned short)(v.w & 0xffffu)); x2 = b2f((unsigned short)(v.w >> 16));
    r.w = cvtpk((x1 * cb.z - x2 * cb.w) * sc, (x1 * cb.w + x2 * cb.z) * sc);
  }
  *reinterpret_cast<uint4*>(pp) = r;
}

// ---------------- flash attention v4 ---------------------------------------
// Swapped QK^T; K staged in LDS (dbuf, src-swizzled global_load_lds); V^T
// fragments read DIRECTLY from global (L2-resident per bh; XCD swizzle keeps
// each bh on one XCD's L2). P tile [16][64] XOR-swizzled, cvt_pk packing,
// max3 reduce, setprio around MFMA clusters. LDS 24KB + VGPR<=128 so all
// 1024 blocks are co-resident (single dispatch wave).
static __device__ __forceinline__ void attn_tile(
    const unsigned short* __restrict__ kt, const bf16x8* __restrict__ vf,
    unsigned short* __restrict__ pl, int la, int lg, int kq, bool diag,
    bf16x8 q0, bf16x8 q1, float& m, float& l, f32x4* o) {
  // S^T = K Q^T : per nb, A-frag rows = keys nb*16+la, B-frag rows = q
  f32x4 st[4];
  __builtin_amdgcn_s_setprio(1);
#pragma unroll
  for (int nb = 0; nb < 4; ++nb) {
    int krow = nb * 16 + la;
    bf16x8 k0 = *reinterpret_cast<const bf16x8*>(&kt[krow * 64 + ((lg ^ (krow & 7)) << 3)]);
    bf16x8 k1 = *reinterpret_cast<const bf16x8*>(&kt[krow * 64 + (((4 + lg) ^ (krow & 7)) << 3)]);
    f32x4 s = (f32x4){0.f, 0.f, 0.f, 0.f};
    s = __builtin_amdgcn_mfma_f32_16x16x32_bf16(k0, q0, s, 0, 0, 0);
    s = __builtin_amdgcn_mfma_f32_16x16x32_bf16(k1, q1, s, 0, 0, 0);
    st[nb] = s;
  }
  __builtin_amdgcn_s_setprio(0);
  // lane (la,lg) holds S^T[key = nb*16+lg*4+j][q = la], pre-scaled (Q folded)
  float sv[16];
#pragma unroll
  for (int nb = 0; nb < 4; ++nb)
#pragma unroll
    for (int j = 0; j < 4; ++j) {
      float v = st[nb][j];
      if (diag && (nb * 16 + j) > kq) v = -1e30f;  // key_in > q_in
      sv[nb * 4 + j] = v;
    }
  // max tree shaped for v_max3 fusion
  float t1 = fmaxf(fmaxf(sv[0], sv[1]), sv[2]);
  float t2 = fmaxf(fmaxf(sv[3], sv[4]), sv[5]);
  float t3 = fmaxf(fmaxf(sv[6], sv[7]), sv[8]);
  float t4 = fmaxf(fmaxf(sv[9], sv[10]), sv[11]);
  float t5 = fmaxf(fmaxf(sv[12], sv[13]), sv[14]);
  float tm = fmaxf(fmaxf(fmaxf(t1, t2), t3), fmaxf(fmaxf(t4, t5), sv[15]));
  tm = fmaxf(tm, __shfl_xor(tm, 16));
  tm = fmaxf(tm, __shfl_xor(tm, 32));
  // defer-max: only rescale when tile max grows past m + 8 (exp2 units)
  if (!__all(tm <= m + 8.0f)) {
    float mnew = fmaxf(m, tm);
    float corr = fexp2(m - mnew);
    m = mnew;
    l *= corr;
#pragma unroll
    for (int j = 0; j < 4; ++j) {
      float cj = __shfl(corr, lg * 4 + j);  // stats for q-row lg*4+j live in lane lg*4+j
#pragma unroll
      for (int db = 0; db < 4; ++db) o[db][j] *= cj;
    }
  }
  float rs0 = 0.f, rs1 = 0.f;
  unsigned int pk[8];
#pragma unroll
  for (int i = 0; i < 8; ++i) {
    float p0 = fexp2(sv[2 * i] - m);
    float p1 = fexp2(sv[2 * i + 1] - m);
    rs0 += p0; rs1 += p1;
    pk[i] = cvtpk(p0, p1);
  }
  float rs = rs0 + rs1;
  rs += __shfl_xor(rs, 16);
  rs += __shfl_xor(rs, 32);
  l += rs;
  // P^T regs -> P[q][key] in LDS, XOR-swizzled [16][64] (2-way max conflicts)
  char* pw = (char*)pl + la * 128;
  int sw = (la & 7) << 4;
#pragma unroll
  for (int nb = 0; nb < 4; ++nb) {
    uint2 wv; wv.x = pk[nb * 2]; wv.y = pk[nb * 2 + 1];
    *reinterpret_cast<uint2*>(pw + (((nb * 32 + lg * 8) ^ sw))) = wv;
  }
  __builtin_amdgcn_s_setprio(1);
#pragma unroll
  for (int kk = 0; kk < 2; ++kk) {
    bf16x8 pa = *reinterpret_cast<const bf16x8*>(pw + ((kk * 64 + lg * 16) ^ sw));
#pragma unroll
    for (int db = 0; db < 4; ++db)
      o[db] = __builtin_amdgcn_mfma_f32_16x16x32_bf16(pa, vf[db * 2 + kk], o[db], 0, 0, 0);
  }
  __builtin_amdgcn_s_setprio(0);
}

__global__ __launch_bounds__(256, 4) void attn_kernel(const unsigned short* __restrict__ Qh,
                                                      const unsigned short* __restrict__ Kh,
                                                      const unsigned short* __restrict__ Vt,
                                                      unsigned short* __restrict__ outA) {
  __shared__ unsigned short kbuf[2][4096];
  __shared__ unsigned short plds[4][1024];
  // XCD swizzle: all 16 blocks of a bh land on one XCD (KV stays in its L2)
  int orig = blockIdx.x;
  int xcd = orig & 7, ix = orig >> 3;
  int bh = xcd * 8 + (ix >> 4);
  int p = ix & 15;
  int qtA = p, qtB = 31 - p;
  int t = threadIdx.x, lane = t & 63, w = t >> 6;
  int la = lane & 15, lg = lane >> 4;
  int kq = w * 16 + la - lg * 4;
  const unsigned short* Qp = Qh + (size_t)bh * SS * DK;
  const unsigned short* Kp = Kh + (size_t)bh * SS * DK;
  const unsigned short* Vtp = Vt + (size_t)bh * DK * SS;
  unsigned short* plw = plds[w];

  int qrA = qtA * 64 + w * 16;
  int qrB = qtB * 64 + w * 16;
  bf16x8 qA0 = *reinterpret_cast<const bf16x8*>(Qp + (size_t)(qrA + la) * 64 + lg * 8);
  bf16x8 qA1 = *reinterpret_cast<const bf16x8*>(Qp + (size_t)(qrA + la) * 64 + 32 + lg * 8);
  bf16x8 qB0 = *reinterpret_cast<const bf16x8*>(Qp + (size_t)(qrB + la) * 64 + lg * 8);
  bf16x8 qB1 = *reinterpret_cast<const bf16x8*>(Qp + (size_t)(qrB + la) * 64 + 32 + lg * 8);

  f32x4 oA[4], oB[4];
#pragma unroll
  for (int i = 0; i < 4; ++i) {
    oA[i] = (f32x4){0.f, 0.f, 0.f, 0.f};
    oB[i] = (f32x4){0.f, 0.f, 0.f, 0.f};
  }
  float mA = -1e30f, lA = 0.f, mB = -1e30f, lB = 0.f;

  int c8 = t & 7, r0 = t >> 3;
  auto stageK = [&](int bi, int kv) {
    int kvBase = kv * 64;
#pragma unroll
    for (int i = 0; i < 2; ++i) {
      int r = r0 + i * 32;
      gl_lds16(Kp + (size_t)(kvBase + r) * 64 + ((c8 ^ (r & 7)) << 3),
               &kbuf[bi][t * 8 + i * 2048]);
    }
  };

  stageK(0, 0);
  __syncthreads();
  int cur = 0;
  for (int kv = 0; kv <= qtB; ++kv) {
    int kvBase = kv * 64;
    if (kv < qtB) stageK(cur ^ 1, kv + 1);  // prefetch next K tile
    // V^T fragments straight from global (L2-hit); shared by tiles A and B
    bf16x8 vf[8];
#pragma unroll
    for (int db = 0; db < 4; ++db)
#pragma unroll
      for (int kk = 0; kk < 2; ++kk)
        vf[db * 2 + kk] = *reinterpret_cast<const bf16x8*>(
            Vtp + (size_t)(db * 16 + la) * SS + kvBase + kk * 32 + lg * 8);
    attn_tile(kbuf[cur], vf, plw, la, lg, kq, kv == qtB, qB0, qB1, mB, lB, oB);
    if (kv <= qtA)
      attn_tile(kbuf[cur], vf, plw, la, lg, kq, kv == qtA, qA0, qA1, mA, lA, oA);
    __syncthreads();  // prefetch landed + all waves done with kbuf[cur]
    cur ^= 1;
  }

  // epilogue: normalize, write bf16 to (b, s, h*64+d) for final GEMM
  int b = bh >> 4, h = bh & 15;
#pragma unroll
  for (int j = 0; j < 4; ++j) {
    float ljB = __shfl(lB, lg * 4 + j);
    float ljA = __shfl(lA, lg * 4 + j);
    float riB = 1.0f / ljB, riA = 1.0f / ljA;
    int qB_ = qrB + lg * 4 + j;
    int qA_ = qrA + lg * 4 + j;
#pragma unroll
    for (int db = 0; db < 4; ++db) {
      outA[((size_t)(b * SS + qB_)) * D_MODEL + h * DK + db * 16 + la] = f2b(oB[db][j] * riB);
      outA[((size_t)(b * SS + qA_)) * D_MODEL + h * DK + db * 16 + la] = f2b(oA[db][j] * riA);
    }
  }
}

extern "C" void kernel_launch(void* const* d_in, const int* in_sizes, int n_in,
                              void* d_out, int out_size, void* d_ws, size_t ws_size,
                              hipStream_t stream) {
  (void)in_sizes; (void)n_in; (void)out_size; (void)ws_size;
  const float* x  = (const float*)d_in[0];
  const float* Wq = (const float*)d_in[1];
  const float* Wk = (const float*)d_in[2];
  const float* Wv = (const float*)d_in[3];
  const float* Wo = (const float*)d_in[4];
  const int* pos  = (const int*)d_in[5];

  char* ws = (char*)d_ws;
  unsigned short* xb    = (unsigned short*)(ws);               // 16 MB: x bf16 [8192][1024]
  unsigned short* Wcat  = (unsigned short*)(ws + 16777216);    // 6 MB Wq|Wk|Wv + 2 MB Wo
  unsigned short* Qh    = (unsigned short*)(ws + 25165824);    // Q,K (b,h,s,d); V^T (b,h,d,s)
  unsigned short* attnO = (unsigned short*)(ws + 75497472);    // 16 MB: (b,s,1024) bf16
  float2* ctab          = (float2*)(ws + 92274688);            // 512 KB trig table

  rope_table_kernel<<<256, 256, 0, stream>>>(pos, ctab);
  cast_kernel<<<8192, 256, 0, stream>>>(x, xb, 2097152);
  cast4_kernel<<<4096, 256, 0, stream>>>(Wq, Wk, Wv, Wo, Wcat);

  gemm_bt<1><<<dim3(64, 24), 256, 0, stream>>>(xb, Wcat, Qh, 3072);
  rope_kernel<<<8192, 256, 0, stream>>>(Qh, Qh + 8388608, ctab);
  attn_kernel<<<1024, 256, 0, stream>>>(Qh, Qh + 8388608, Qh + 16777216, attnO);
  gemm_bt<0><<<dim3(64, 8), 256, 0, stream>>>(attnO, Wcat + 3145728, (float*)d_out, 1024);
}

// Round 7
// 251.430 us; speedup vs baseline: 1.1009x; 1.1009x over previous
//
#include <hip/hip_runtime.h>
#include <hip/hip_bf16.h>

#define GAS __attribute__((address_space(1)))
#define LAS __attribute__((address_space(3)))

typedef __attribute__((ext_vector_type(8))) short bf16x8;
typedef __attribute__((ext_vector_type(4))) float f32x4;

#define D_MODEL 1024
#define NHEADS 16
#define DK 64
#define BB 4
#define SS 2048

#define SM_SCALE 0.18033688011112042f  /* 1/sqrt(64) * log2(e), folded into Q at RoPE */

static __device__ __forceinline__ float b2f(unsigned short u) {
  union { unsigned int i; float f; } c; c.i = ((unsigned int)u) << 16; return c.f;
}
static __device__ __forceinline__ unsigned short f2b(float f) {
  union { float f; unsigned int i; } c; c.f = f;
  unsigned int x = c.i;
  x += 0x7fffu + ((x >> 16) & 1u);   // RNE
  return (unsigned short)(x >> 16);
}
// pack 2 f32 -> 2 bf16 (RNE) in one instruction
static __device__ __forceinline__ unsigned int cvtpk(float lo, float hi) {
  unsigned int r;
  asm("v_cvt_pk_bf16_f32 %0, %1, %2" : "=v"(r) : "v"(lo), "v"(hi));
  return r;
}
// raw 2^x (hardware v_exp_f32)
static __device__ __forceinline__ float fexp2(float x) {
  float r;
  asm("v_exp_f32 %0, %1" : "=v"(r) : "v"(x));
  return r;
}

// ---------------- cast f32 -> bf16 (vectorized float4 -> ushort4) ----------
__global__ __launch_bounds__(256) void cast_kernel(const float* __restrict__ in,
                                                   unsigned short* __restrict__ out,
                                                   int n4) {
  int i = blockIdx.x * 256 + threadIdx.x;
  if (i >= n4) return;
  float4 v = reinterpret_cast<const float4*>(in)[i];
  ushort4 o;
  o.x = f2b(v.x); o.y = f2b(v.y); o.z = f2b(v.z); o.w = f2b(v.w);
  reinterpret_cast<ushort4*>(out)[i] = o;
}

// all 4 weight matrices in one launch; dst regions are contiguous in ws
__global__ __launch_bounds__(256) void cast4_kernel(const float* __restrict__ a,
                                                    const float* __restrict__ b,
                                                    const float* __restrict__ c,
                                                    const float* __restrict__ d,
                                                    unsigned short* __restrict__ out) {
  int i = blockIdx.x * 256 + threadIdx.x;  // < 4 * 262144
  int which = i >> 18, off = i & 0x3ffff;
  const float* src = which == 0 ? a : which == 1 ? b : which == 2 ? c : d;
  float4 v = reinterpret_cast<const float4*>(src)[off];
  ushort4 o;
  o.x = f2b(v.x); o.y = f2b(v.y); o.z = f2b(v.z); o.w = f2b(v.w);
  reinterpret_cast<ushort4*>(out)[i] = o;
}

// ---------------- bf16 GEMM, C = A (M x K) * B^T (N x K), K = 1024 --------
static __device__ __forceinline__ void gl_lds16(const void* g, void* l) {
  __builtin_amdgcn_global_load_lds((const GAS unsigned int*)g,
                                   (LAS unsigned int*)l, 16, 0, 0);
}

template <int EPI>
__global__ __launch_bounds__(256) void gemm_bt(const unsigned short* __restrict__ A,
                                               const unsigned short* __restrict__ Bw,
                                               void* __restrict__ outp, int N) {
  const int K = 1024;
  __shared__ unsigned short lds_a[128 * 32];
  __shared__ unsigned short lds_b[128 * 32];
  int t = threadIdx.x;
  int lane = t & 63;
  int w = t >> 6, wr = w >> 1, wc = w & 1;
  int la = lane & 15, lg = lane >> 4;
  // T1 XCD swizzle: contiguous chunk of linear block ids per XCD (nwg % 8 == 0)
  int nwg = gridDim.x * gridDim.y;
  int lid = blockIdx.y * gridDim.x + blockIdx.x;
  int nl = (lid & 7) * (nwg >> 3) + (lid >> 3);
  int bx = nl % gridDim.x, by = nl / gridDim.x;
  int rowBase = bx * 128;
  int colBase = by * 128;
  const unsigned short* Ab = A + (size_t)(rowBase + (t >> 2)) * K + (t & 3) * 8;
  const unsigned short* Bb = Bw + (size_t)(colBase + (t >> 2)) * K + (t & 3) * 8;

  f32x4 acc[4][4];
#pragma unroll
  for (int i = 0; i < 4; ++i)
#pragma unroll
    for (int j = 0; j < 4; ++j) acc[i][j] = (f32x4){0.f, 0.f, 0.f, 0.f};

  for (int k0 = 0; k0 < K; k0 += 32) {
    gl_lds16(Ab + k0, &lds_a[t * 8]);
    gl_lds16(Ab + (size_t)64 * K + k0, &lds_a[2048 + t * 8]);
    gl_lds16(Bb + k0, &lds_b[t * 8]);
    gl_lds16(Bb + (size_t)64 * K + k0, &lds_b[2048 + t * 8]);
    __syncthreads();
    bf16x8 af[4], bfr[4];
#pragma unroll
    for (int mi = 0; mi < 4; ++mi)
      af[mi] = *reinterpret_cast<const bf16x8*>(&lds_a[(wr * 64 + mi * 16 + la) * 32 + lg * 8]);
#pragma unroll
    for (int ni = 0; ni < 4; ++ni)
      bfr[ni] = *reinterpret_cast<const bf16x8*>(&lds_b[(wc * 64 + ni * 16 + la) * 32 + lg * 8]);
#pragma unroll
    for (int mi = 0; mi < 4; ++mi)
#pragma unroll
      for (int ni = 0; ni < 4; ++ni)
        acc[mi][ni] = __builtin_amdgcn_mfma_f32_16x16x32_bf16(af[mi], bfr[ni], acc[mi][ni], 0, 0, 0);
    __syncthreads();
  }

  if (EPI == 0) {
    float* out = (float*)outp;
#pragma unroll
    for (int mi = 0; mi < 4; ++mi)
#pragma unroll
      for (int ni = 0; ni < 4; ++ni)
#pragma unroll
        for (int j = 0; j < 4; ++j) {
          int row = rowBase + wr * 64 + mi * 16 + lg * 4 + j;
          int col = colBase + wc * 64 + ni * 16 + la;
          out[(size_t)row * N + col] = acc[mi][ni][j];
        }
  } else {
    // Q,K: [which][b,h,s,d].  V: transposed [b,h,d,s].
    unsigned short* qkv = (unsigned short*)outp;
#pragma unroll
    for (int mi = 0; mi < 4; ++mi)
#pragma unroll
      for (int ni = 0; ni < 4; ++ni)
#pragma unroll
        for (int j = 0; j < 4; ++j) {
          int row = rowBase + wr * 64 + mi * 16 + lg * 4 + j;
          int col = colBase + wc * 64 + ni * 16 + la;
          int which = col >> 10, d = col & 1023;
          int h = d >> 6, dd = d & 63;
          int b = row >> 11, s = row & 2047;
          size_t off;
          if (which == 2)
            off = (size_t)2 * 8388608 +
                  ((size_t)(b * NHEADS + h) * DK + dd) * SS + s;
          else
            off = (size_t)which * 8388608 +
                  ((size_t)(b * NHEADS + h) * SS + s) * DK + dd;
          qkv[off] = f2b(acc[mi][ni][j]);
        }
  }
}

// ---------------- RoPE: trig table + vectorized apply ----------------------
__global__ __launch_bounds__(256) void rope_table_kernel(const int* __restrict__ pos,
                                                         float2* __restrict__ ctab) {
  int i = blockIdx.x * 256 + threadIdx.x;  // 2048 * 32
  int s = i >> 5, pr = i & 31;
  float p = (float)pos[s];
  float ang = p * __expf(-(float)pr * 0.2878231366242557f);  // ln(1e4)/32
  float sn, cs;
  sincosf(ang, &sn, &cs);
  ctab[i] = make_float2(cs, sn);
}

// each thread: 4 pairs (16B). Q rows scaled by SM_SCALE.
__global__ __launch_bounds__(256) void rope_kernel(unsigned short* __restrict__ Q,
                                                   unsigned short* __restrict__ Kk,
                                                   const float2* __restrict__ ctab) {
  int i = blockIdx.x * 256 + threadIdx.x;  // < 2 * 64*2048*8 = 2097152
  int seg = i & 7;
  int row = (i >> 3) & 131071;  // bh*2048 + s
  int isK = i >> 20;
  unsigned short* base = isK ? Kk : Q;
  int s = row & 2047;
  float sc = isK ? 1.0f : SM_SCALE;
  const float4* ct4 = reinterpret_cast<const float4*>(ctab + s * 32 + seg * 4);
  float4 ca = ct4[0], cb = ct4[1];  // (c0,s0,c1,s1), (c2,s2,c3,s3)
  unsigned int* pp = reinterpret_cast<unsigned int*>(base + (size_t)row * 64 + seg * 8);
  uint4 v = *reinterpret_cast<uint4*>(pp);
  uint4 r;
  {
    float x1 = b2f((unsigned short)(v.x & 0xffffu)), x2 = b2f((unsigned short)(v.x >> 16));
    r.x = cvtpk((x1 * ca.x - x2 * ca.y) * sc, (x1 * ca.y + x2 * ca.x) * sc);
    x1 = b2f((unsigned short)(v.y & 0xffffu)); x2 = b2f((unsigned short)(v.y >> 16));
    r.y = cvtpk((x1 * ca.z - x2 * ca.w) * sc, (x1 * ca.w + x2 * ca.z) * sc);
    x1 = b2f((unsigned short)(v.z & 0xffffu)); x2 = b2f((unsigned short)(v.z >> 16));
    r.z = cvtpk((x1 * cb.x - x2 * cb.y) * sc, (x1 * cb.y + x2 * cb.x) * sc);
    x1 = b2f((unsigned short)(v.w & 0xffffu)); x2 = b2f((unsigned short)(v.w >> 16));
    r.w = cvtpk((x1 * cb.z - x2 * cb.w) * sc, (x1 * cb.w + x2 * cb.z) * sc);
  }
  *reinterpret_cast<uint4*>(pp) = r;
}

// ---------------- flash attention v5 ---------------------------------------
// R4's LDS-staged K+V (dbuf, src-swizzled global_load_lds) + R6's VALU opts
// (cvt_pk, max3 tree, swizzled 8KB P, fexp2, setprio, XCD swizzle).
// LDS 40KB + launch_bounds(256,4) -> 4 blocks/CU, single dispatch wave.
// Both q-tiles' QK^T clustered before either softmax (dual-chain ILP).
static __device__ __forceinline__ void qkt_tile(
    const unsigned short* __restrict__ kt, int la, int lg,
    bf16x8 q0, bf16x8 q1, f32x4* st) {
#pragma unroll
  for (int nb = 0; nb < 4; ++nb) {
    int krow = nb * 16 + la;
    bf16x8 k0 = *reinterpret_cast<const bf16x8*>(&kt[krow * 64 + ((lg ^ (krow & 7)) << 3)]);
    bf16x8 k1 = *reinterpret_cast<const bf16x8*>(&kt[krow * 64 + (((4 + lg) ^ (krow & 7)) << 3)]);
    f32x4 s = (f32x4){0.f, 0.f, 0.f, 0.f};
    s = __builtin_amdgcn_mfma_f32_16x16x32_bf16(k0, q0, s, 0, 0, 0);
    s = __builtin_amdgcn_mfma_f32_16x16x32_bf16(k1, q1, s, 0, 0, 0);
    st[nb] = s;
  }
}

static __device__ __forceinline__ void smpv_tile(
    const f32x4* __restrict__ st, const unsigned short* __restrict__ vt,
    unsigned short* __restrict__ pl, int la, int lg, int kq, bool diag,
    float& m, float& l, f32x4* o) {
  // lane (la,lg) holds S^T[key = nb*16+lg*4+j][q = la], pre-scaled (Q folded)
  float sv[16];
#pragma unroll
  for (int nb = 0; nb < 4; ++nb)
#pragma unroll
    for (int j = 0; j < 4; ++j) {
      float v = st[nb][j];
      if (diag && (nb * 16 + j) > kq) v = -1e30f;  // key_in > q_in
      sv[nb * 4 + j] = v;
    }
  // max tree shaped for v_max3 fusion
  float t1 = fmaxf(fmaxf(sv[0], sv[1]), sv[2]);
  float t2 = fmaxf(fmaxf(sv[3], sv[4]), sv[5]);
  float t3 = fmaxf(fmaxf(sv[6], sv[7]), sv[8]);
  float t4 = fmaxf(fmaxf(sv[9], sv[10]), sv[11]);
  float t5 = fmaxf(fmaxf(sv[12], sv[13]), sv[14]);
  float tm = fmaxf(fmaxf(fmaxf(t1, t2), t3), fmaxf(fmaxf(t4, t5), sv[15]));
  tm = fmaxf(tm, __shfl_xor(tm, 16));
  tm = fmaxf(tm, __shfl_xor(tm, 32));
  // defer-max: only rescale when tile max grows past m + 8 (exp2 units)
  if (!__all(tm <= m + 8.0f)) {
    float mnew = fmaxf(m, tm);
    float corr = fexp2(m - mnew);
    m = mnew;
    l *= corr;
#pragma unroll
    for (int j = 0; j < 4; ++j) {
      float cj = __shfl(corr, lg * 4 + j);  // stats for q-row lg*4+j live in lane lg*4+j
#pragma unroll
      for (int db = 0; db < 4; ++db) o[db][j] *= cj;
    }
  }
  float rs0 = 0.f, rs1 = 0.f;
  unsigned int pk[8];
#pragma unroll
  for (int i = 0; i < 8; ++i) {
    float p0 = fexp2(sv[2 * i] - m);
    float p1 = fexp2(sv[2 * i + 1] - m);
    rs0 += p0; rs1 += p1;
    pk[i] = cvtpk(p0, p1);
  }
  float rs = rs0 + rs1;
  rs += __shfl_xor(rs, 16);
  rs += __shfl_xor(rs, 32);
  l += rs;
  // P^T regs -> P[q][key] in LDS, XOR-swizzled [16][64] (2-way max conflicts)
  char* pw = (char*)pl + la * 128;
  int sw = (la & 7) << 4;
#pragma unroll
  for (int nb = 0; nb < 4; ++nb) {
    uint2 wv; wv.x = pk[nb * 2]; wv.y = pk[nb * 2 + 1];
    *reinterpret_cast<uint2*>(pw + (((nb * 32 + lg * 8) ^ sw))) = wv;
  }
  __builtin_amdgcn_s_setprio(1);
#pragma unroll
  for (int kk = 0; kk < 2; ++kk) {
    bf16x8 pa = *reinterpret_cast<const bf16x8*>(pw + ((kk * 64 + lg * 16) ^ sw));
#pragma unroll
    for (int db = 0; db < 4; ++db) {
      int vrow = db * 16 + la;
      bf16x8 vb = *reinterpret_cast<const bf16x8*>(&vt[vrow * 64 + (((kk * 4 + lg) ^ (vrow & 7)) << 3)]);
      o[db] = __builtin_amdgcn_mfma_f32_16x16x32_bf16(pa, vb, o[db], 0, 0, 0);
    }
  }
  __builtin_amdgcn_s_setprio(0);
}

__global__ __launch_bounds__(256, 4) void attn_kernel(const unsigned short* __restrict__ Qh,
                                                      const unsigned short* __restrict__ Kh,
                                                      const unsigned short* __restrict__ Vt,
                                                      unsigned short* __restrict__ outA) {
  __shared__ unsigned short kbuf[2][4096];
  __shared__ unsigned short vbuf[2][4096];
  __shared__ unsigned short plds[4][1024];
  // XCD swizzle: all 16 blocks of a bh land on one XCD (KV stays in its L2)
  int orig = blockIdx.x;
  int xcd = orig & 7, ix = orig >> 3;
  int bh = xcd * 8 + (ix >> 4);
  int p = ix & 15;
  int qtA = p, qtB = 31 - p;
  int t = threadIdx.x, lane = t & 63, w = t >> 6;
  int la = lane & 15, lg = lane >> 4;
  int kq = w * 16 + la - lg * 4;
  const unsigned short* Qp = Qh + (size_t)bh * SS * DK;
  const unsigned short* Kp = Kh + (size_t)bh * SS * DK;
  const unsigned short* Vtp = Vt + (size_t)bh * DK * SS;
  unsigned short* plw = plds[w];

  int qrA = qtA * 64 + w * 16;
  int qrB = qtB * 64 + w * 16;
  bf16x8 qA0 = *reinterpret_cast<const bf16x8*>(Qp + (size_t)(qrA + la) * 64 + lg * 8);
  bf16x8 qA1 = *reinterpret_cast<const bf16x8*>(Qp + (size_t)(qrA + la) * 64 + 32 + lg * 8);
  bf16x8 qB0 = *reinterpret_cast<const bf16x8*>(Qp + (size_t)(qrB + la) * 64 + lg * 8);
  bf16x8 qB1 = *reinterpret_cast<const bf16x8*>(Qp + (size_t)(qrB + la) * 64 + 32 + lg * 8);

  f32x4 oA[4], oB[4];
#pragma unroll
  for (int i = 0; i < 4; ++i) {
    oA[i] = (f32x4){0.f, 0.f, 0.f, 0.f};
    oB[i] = (f32x4){0.f, 0.f, 0.f, 0.f};
  }
  float mA = -1e30f, lA = 0.f, mB = -1e30f, lB = 0.f;

  int c8 = t & 7, r0 = t >> 3;
  auto stage = [&](int bi, int kv) {
    int kvBase = kv * 64;
#pragma unroll
    for (int i = 0; i < 2; ++i) {
      int r = r0 + i * 32;
      gl_lds16(Kp + (size_t)(kvBase + r) * 64 + ((c8 ^ (r & 7)) << 3),
               &kbuf[bi][t * 8 + i * 2048]);
      gl_lds16(Vtp + (size_t)r * SS + kvBase + ((c8 ^ (r & 7)) << 3),
               &vbuf[bi][t * 8 + i * 2048]);
    }
  };

  stage(0, 0);
  __syncthreads();
  int cur = 0;
  for (int kv = 0; kv <= qtB; ++kv) {
    if (kv < qtB) stage(cur ^ 1, kv + 1);  // prefetch next K/V tile
    bool doA = (kv <= qtA);
    // cluster both tiles' QK^T MFMAs (independent chains -> scheduler ILP)
    f32x4 stB[4], stA[4];
    __builtin_amdgcn_s_setprio(1);
    qkt_tile(kbuf[cur], la, lg, qB0, qB1, stB);
    if (doA) qkt_tile(kbuf[cur], la, lg, qA0, qA1, stA);
    __builtin_amdgcn_s_setprio(0);
    smpv_tile(stB, vbuf[cur], plw, la, lg, kq, kv == qtB, mB, lB, oB);
    if (doA)
      smpv_tile(stA, vbuf[cur], plw, la, lg, kq, kv == qtA, mA, lA, oA);
    __syncthreads();  // prefetch landed + all waves done with buf[cur]
    cur ^= 1;
  }

  // epilogue: normalize, write bf16 to (b, s, h*64+d) for final GEMM
  int b = bh >> 4, h = bh & 15;
#pragma unroll
  for (int j = 0; j < 4; ++j) {
    float ljB = __shfl(lB, lg * 4 + j);
    float ljA = __shfl(lA, lg * 4 + j);
    float riB = 1.0f / ljB, riA = 1.0f / ljA;
    int qB_ = qrB + lg * 4 + j;
    int qA_ = qrA + lg * 4 + j;
#pragma unroll
    for (int db = 0; db < 4; ++db) {
      outA[((size_t)(b * SS + qB_)) * D_MODEL + h * DK + db * 16 + la] = f2b(oB[db][j] * riB);
      outA[((size_t)(b * SS + qA_)) * D_MODEL + h * DK + db * 16 + la] = f2b(oA[db][j] * riA);
    }
  }
}

extern "C" void kernel_launch(void* const* d_in, const int* in_sizes, int n_in,
                              void* d_out, int out_size, void* d_ws, size_t ws_size,
                              hipStream_t stream) {
  (void)in_sizes; (void)n_in; (void)out_size; (void)ws_size;
  const float* x  = (const float*)d_in[0];
  const float* Wq = (const float*)d_in[1];
  const float* Wk = (const float*)d_in[2];
  const float* Wv = (const float*)d_in[3];
  const float* Wo = (const float*)d_in[4];
  const int* pos  = (const int*)d_in[5];

  char* ws = (char*)d_ws;
  unsigned short* xb    = (unsigned short*)(ws);               // 16 MB: x bf16 [8192][1024]
  unsigned short* Wcat  = (unsigned short*)(ws + 16777216);    // 6 MB Wq|Wk|Wv + 2 MB Wo
  unsigned short* Qh    = (unsigned short*)(ws + 25165824);    // Q,K (b,h,s,d); V^T (b,h,d,s)
  unsigned short* attnO = (unsigned short*)(ws + 75497472);    // 16 MB: (b,s,1024) bf16
  float2* ctab          = (float2*)(ws + 92274688);            // 512 KB trig table

  rope_table_kernel<<<256, 256, 0, stream>>>(pos, ctab);
  cast_kernel<<<8192, 256, 0, stream>>>(x, xb, 2097152);
  cast4_kernel<<<4096, 256, 0, stream>>>(Wq, Wk, Wv, Wo, Wcat);

  gemm_bt<1><<<dim3(64, 24), 256, 0, stream>>>(xb, Wcat, Qh, 3072);
  rope_kernel<<<8192, 256, 0, stream>>>(Qh, Qh + 8388608, ctab);
  attn_kernel<<<1024, 256, 0, stream>>>(Qh, Qh + 8388608, Qh + 16777216, attnO);
  gemm_bt<0><<<dim3(64, 8), 256, 0, stream>>>(attnO, Wcat + 3145728, (float*)d_out, 1024);
}

// Round 9
// 247.257 us; speedup vs baseline: 1.1195x; 1.0169x over previous
//
#include <hip/hip_runtime.h>
#include <hip/hip_bf16.h>

#define GAS __attribute__((address_space(1)))
#define LAS __attribute__((address_space(3)))

typedef __attribute__((ext_vector_type(8))) short bf16x8;
typedef __attribute__((ext_vector_type(4))) float f32x4;

#define D_MODEL 1024
#define NHEADS 16
#define DK 64
#define BB 4
#define SS 2048

#define SM_SCALE 0.18033688011112042f  /* 1/sqrt(64) * log2(e), folded into Q at RoPE */

static __device__ __forceinline__ float b2f(unsigned short u) {
  union { unsigned int i; float f; } c; c.i = ((unsigned int)u) << 16; return c.f;
}
static __device__ __forceinline__ unsigned short f2b(float f) {
  union { float f; unsigned int i; } c; c.f = f;
  unsigned int x = c.i;
  x += 0x7fffu + ((x >> 16) & 1u);   // RNE
  return (unsigned short)(x >> 16);
}
// pack 2 f32 -> 2 bf16 (RNE) in one instruction
static __device__ __forceinline__ unsigned int cvtpk(float lo, float hi) {
  unsigned int r;
  asm("v_cvt_pk_bf16_f32 %0, %1, %2" : "=v"(r) : "v"(lo), "v"(hi));
  return r;
}
// raw 2^x (hardware v_exp_f32)
static __device__ __forceinline__ float fexp2(float x) {
  float r;
  asm("v_exp_f32 %0, %1" : "=v"(r) : "v"(x));
  return r;
}

// ---------------- cast f32 -> bf16 (vectorized float4 -> ushort4) ----------
__global__ __launch_bounds__(256) void cast_kernel(const float* __restrict__ in,
                                                   unsigned short* __restrict__ out,
                                                   int n4) {
  int i = blockIdx.x * 256 + threadIdx.x;
  if (i >= n4) return;
  float4 v = reinterpret_cast<const float4*>(in)[i];
  ushort4 o;
  o.x = f2b(v.x); o.y = f2b(v.y); o.z = f2b(v.z); o.w = f2b(v.w);
  reinterpret_cast<ushort4*>(out)[i] = o;
}

// all 4 weight matrices in one launch; dst regions are contiguous in ws
__global__ __launch_bounds__(256) void cast4_kernel(const float* __restrict__ a,
                                                    const float* __restrict__ b,
                                                    const float* __restrict__ c,
                                                    const float* __restrict__ d,
                                                    unsigned short* __restrict__ out) {
  int i = blockIdx.x * 256 + threadIdx.x;  // < 4 * 262144
  int which = i >> 18, off = i & 0x3ffff;
  const float* src = which == 0 ? a : which == 1 ? b : which == 2 ? c : d;
  float4 v = reinterpret_cast<const float4*>(src)[off];
  ushort4 o;
  o.x = f2b(v.x); o.y = f2b(v.y); o.z = f2b(v.z); o.w = f2b(v.w);
  reinterpret_cast<ushort4*>(out)[i] = o;
}

// ---------------- bf16 GEMM v2: C = A (M x K) * B^T (N x K), K = 1024 ------
// 128x256 tile, BK=64, 512 threads = 8 waves (2M x 4N), 64x64 per wave.
// Double-buffered LDS (96 KB), chunk-XOR swizzle (write via pre-swizzled
// global_load_lds source, read with same XOR -> 2-way bank = free).
// Schedule: STAGE(t+1) -> compute(t) -> barrier (drain-late prefetch).
static __device__ __forceinline__ void gl_lds16(const void* g, void* l) {
  __builtin_amdgcn_global_load_lds((const GAS unsigned int*)g,
                                   (LAS unsigned int*)l, 16, 0, 0);
}

template <int EPI>
__global__ __launch_bounds__(512, 2) void gemm_bt(const unsigned short* __restrict__ A,
                                                  const unsigned short* __restrict__ Bw,
                                                  void* __restrict__ outp, int N) {
  const int K = 1024;
  const int NT = 16;  // K / 64
  __shared__ unsigned short lds_a[2][128 * 64];
  __shared__ unsigned short lds_b[2][256 * 64];
  int t = threadIdx.x;
  int lane = t & 63;
  int w = t >> 6, wr = w >> 2, wc = w & 3;  // 2 x 4 wave grid
  int la = lane & 15, lg = lane >> 4;
  // T1 XCD swizzle: contiguous chunk of linear block ids per XCD (nwg % 8 == 0)
  int nwg = gridDim.x * gridDim.y;
  int lid = blockIdx.y * gridDim.x + blockIdx.x;
  int nl = (lid & 7) * (nwg >> 3) + (lid >> 3);
  int bx = nl % gridDim.x, by = nl / gridDim.x;
  int rowBase = bx * 128;
  int colBase = by * 256;

  int c8 = t & 7, r0 = t >> 3;  // staging: row r0 (+64/round), 16B chunk c8
  const unsigned short* Abase = A + (size_t)rowBase * K;
  const unsigned short* Bbase = Bw + (size_t)colBase * K;
  // LDS layout: row-major [rows][64]; row r group i lives at element r*64.
  // dest element = t*8 + i*4096  (r = (t>>3) + i*64, chunk c8 at +c8*8 = t*8)
  auto stage = [&](int bi, int kt) {
    int k0 = kt * 64;
#pragma unroll
    for (int i = 0; i < 2; ++i) {
      int r = r0 + i * 64;
      gl_lds16(Abase + (size_t)r * K + k0 + ((c8 ^ (r & 7)) << 3),
               &lds_a[bi][t * 8 + i * 4096]);
    }
#pragma unroll
    for (int i = 0; i < 4; ++i) {
      int r = r0 + i * 64;
      gl_lds16(Bbase + (size_t)r * K + k0 + ((c8 ^ (r & 7)) << 3),
               &lds_b[bi][t * 8 + i * 4096]);
    }
  };

  f32x4 acc[4][4];
#pragma unroll
  for (int i = 0; i < 4; ++i)
#pragma unroll
    for (int j = 0; j < 4; ++j) acc[i][j] = (f32x4){0.f, 0.f, 0.f, 0.f};

  stage(0, 0);
  __syncthreads();
  int cur = 0;
  for (int kt = 0; kt < NT; ++kt) {
    if (kt + 1 < NT) stage(cur ^ 1, kt + 1);  // prefetch next K-tile (drains at barrier)
    bf16x8 af[2][4], bfr[2][4];
#pragma unroll
    for (int s = 0; s < 2; ++s)
#pragma unroll
      for (int mi = 0; mi < 4; ++mi) {
        int row = wr * 64 + mi * 16 + la;
        af[s][mi] = *reinterpret_cast<const bf16x8*>(
            &lds_a[cur][row * 64 + (((s * 4 + lg) ^ (row & 7)) << 3)]);
      }
#pragma unroll
    for (int s = 0; s < 2; ++s)
#pragma unroll
      for (int ni = 0; ni < 4; ++ni) {
        int row = wc * 64 + ni * 16 + la;
        bfr[s][ni] = *reinterpret_cast<const bf16x8*>(
            &lds_b[cur][row * 64 + (((s * 4 + lg) ^ (row & 7)) << 3)]);
      }
    __builtin_amdgcn_s_setprio(1);
#pragma unroll
    for (int s = 0; s < 2; ++s)
#pragma unroll
      for (int mi = 0; mi < 4; ++mi)
#pragma unroll
        for (int ni = 0; ni < 4; ++ni)
          acc[mi][ni] = __builtin_amdgcn_mfma_f32_16x16x32_bf16(af[s][mi], bfr[s][ni],
                                                                acc[mi][ni], 0, 0, 0);
    __builtin_amdgcn_s_setprio(0);
    __syncthreads();  // prefetch landed + all waves done reading buf[cur]
    cur ^= 1;
  }

  if (EPI == 0) {
    float* out = (float*)outp;
#pragma unroll
    for (int mi = 0; mi < 4; ++mi)
#pragma unroll
      for (int ni = 0; ni < 4; ++ni)
#pragma unroll
        for (int j = 0; j < 4; ++j) {
          int row = rowBase + wr * 64 + mi * 16 + lg * 4 + j;
          int col = colBase + wc * 64 + ni * 16 + la;
          out[(size_t)row * N + col] = acc[mi][ni][j];
        }
  } else {
    // Q,K: [which][b,h,s,d].  V: transposed [b,h,d,s].
    unsigned short* qkv = (unsigned short*)outp;
#pragma unroll
    for (int mi = 0; mi < 4; ++mi)
#pragma unroll
      for (int ni = 0; ni < 4; ++ni)
#pragma unroll
        for (int j = 0; j < 4; ++j) {
          int row = rowBase + wr * 64 + mi * 16 + lg * 4 + j;
          int col = colBase + wc * 64 + ni * 16 + la;
          int which = col >> 10, d = col & 1023;
          int h = d >> 6, dd = d & 63;
          int b = row >> 11, s = row & 2047;
          size_t off;
          if (which == 2)
            off = (size_t)2 * 8388608 +
                  ((size_t)(b * NHEADS + h) * DK + dd) * SS + s;
          else
            off = (size_t)which * 8388608 +
                  ((size_t)(b * NHEADS + h) * SS + s) * DK + dd;
          qkv[off] = f2b(acc[mi][ni][j]);
        }
  }
}

// ---------------- RoPE: trig table + vectorized apply ----------------------
__global__ __launch_bounds__(256) void rope_table_kernel(const int* __restrict__ pos,
                                                         float2* __restrict__ ctab) {
  int i = blockIdx.x * 256 + threadIdx.x;  // 2048 * 32
  int s = i >> 5, pr = i & 31;
  float p = (float)pos[s];
  float ang = p * __expf(-(float)pr * 0.2878231366242557f);  // ln(1e4)/32
  float sn, cs;
  sincosf(ang, &sn, &cs);
  ctab[i] = make_float2(cs, sn);
}

// each thread: 4 pairs (16B). Q rows scaled by SM_SCALE.
__global__ __launch_bounds__(256) void rope_kernel(unsigned short* __restrict__ Q,
                                                   unsigned short* __restrict__ Kk,
                                                   const float2* __restrict__ ctab) {
  int i = blockIdx.x * 256 + threadIdx.x;  // < 2 * 64*2048*8 = 2097152
  int seg = i & 7;
  int row = (i >> 3) & 131071;  // bh*2048 + s
  int isK = i >> 20;
  unsigned short* base = isK ? Kk : Q;
  int s = row & 2047;
  float sc = isK ? 1.0f : SM_SCALE;
  const float4* ct4 = reinterpret_cast<const float4*>(ctab + s * 32 + seg * 4);
  float4 ca = ct4[0], cb = ct4[1];  // (c0,s0,c1,s1), (c2,s2,c3,s3)
  unsigned int* pp = reinterpret_cast<unsigned int*>(base + (size_t)row * 64 + seg * 8);
  uint4 v = *reinterpret_cast<uint4*>(pp);
  uint4 r;
  {
    float x1 = b2f((unsigned short)(v.x & 0xffffu)), x2 = b2f((unsigned short)(v.x >> 16));
    r.x = cvtpk((x1 * ca.x - x2 * ca.y) * sc, (x1 * ca.y + x2 * ca.x) * sc);
    x1 = b2f((unsigned short)(v.y & 0xffffu)); x2 = b2f((unsigned short)(v.y >> 16));
    r.y = cvtpk((x1 * ca.z - x2 * ca.w) * sc, (x1 * ca.w + x2 * ca.z) * sc);
    x1 = b2f((unsigned short)(v.z & 0xffffu)); x2 = b2f((unsigned short)(v.z >> 16));
    r.z = cvtpk((x1 * cb.x - x2 * cb.y) * sc, (x1 * cb.y + x2 * cb.x) * sc);
    x1 = b2f((unsigned short)(v.w & 0xffffu)); x2 = b2f((unsigned short)(v.w >> 16));
    r.w = cvtpk((x1 * cb.z - x2 * cb.w) * sc, (x1 * cb.w + x2 * cb.z) * sc);
  }
  *reinterpret_cast<uint4*>(pp) = r;
}

// ---------------- flash attention v5 (unchanged from R7) -------------------
static __device__ __forceinline__ void qkt_tile(
    const unsigned short* __restrict__ kt, int la, int lg,
    bf16x8 q0, bf16x8 q1, f32x4* st) {
#pragma unroll
  for (int nb = 0; nb < 4; ++nb) {
    int krow = nb * 16 + la;
    bf16x8 k0 = *reinterpret_cast<const bf16x8*>(&kt[krow * 64 + ((lg ^ (krow & 7)) << 3)]);
    bf16x8 k1 = *reinterpret_cast<const bf16x8*>(&kt[krow * 64 + (((4 + lg) ^ (krow & 7)) << 3)]);
    f32x4 s = (f32x4){0.f, 0.f, 0.f, 0.f};
    s = __builtin_amdgcn_mfma_f32_16x16x32_bf16(k0, q0, s, 0, 0, 0);
    s = __builtin_amdgcn_mfma_f32_16x16x32_bf16(k1, q1, s, 0, 0, 0);
    st[nb] = s;
  }
}

static __device__ __forceinline__ void smpv_tile(
    const f32x4* __restrict__ st, const unsigned short* __restrict__ vt,
    unsigned short* __restrict__ pl, int la, int lg, int kq, bool diag,
    float& m, float& l, f32x4* o) {
  float sv[16];
#pragma unroll
  for (int nb = 0; nb < 4; ++nb)
#pragma unroll
    for (int j = 0; j < 4; ++j) {
      float v = st[nb][j];
      if (diag && (nb * 16 + j) > kq) v = -1e30f;  // key_in > q_in
      sv[nb * 4 + j] = v;
    }
  float t1 = fmaxf(fmaxf(sv[0], sv[1]), sv[2]);
  float t2 = fmaxf(fmaxf(sv[3], sv[4]), sv[5]);
  float t3 = fmaxf(fmaxf(sv[6], sv[7]), sv[8]);
  float t4 = fmaxf(fmaxf(sv[9], sv[10]), sv[11]);
  float t5 = fmaxf(fmaxf(sv[12], sv[13]), sv[14]);
  float tm = fmaxf(fmaxf(fmaxf(t1, t2), t3), fmaxf(fmaxf(t4, t5), sv[15]));
  tm = fmaxf(tm, __shfl_xor(tm, 16));
  tm = fmaxf(tm, __shfl_xor(tm, 32));
  if (!__all(tm <= m + 8.0f)) {
    float mnew = fmaxf(m, tm);
    float corr = fexp2(m - mnew);
    m = mnew;
    l *= corr;
#pragma unroll
    for (int j = 0; j < 4; ++j) {
      float cj = __shfl(corr, lg * 4 + j);
#pragma unroll
      for (int db = 0; db < 4; ++db) o[db][j] *= cj;
    }
  }
  float rs0 = 0.f, rs1 = 0.f;
  unsigned int pk[8];
#pragma unroll
  for (int i = 0; i < 8; ++i) {
    float p0 = fexp2(sv[2 * i] - m);
    float p1 = fexp2(sv[2 * i + 1] - m);
    rs0 += p0; rs1 += p1;
    pk[i] = cvtpk(p0, p1);
  }
  float rs = rs0 + rs1;
  rs += __shfl_xor(rs, 16);
  rs += __shfl_xor(rs, 32);
  l += rs;
  char* pw = (char*)pl + la * 128;
  int sw = (la & 7) << 4;
#pragma unroll
  for (int nb = 0; nb < 4; ++nb) {
    uint2 wv; wv.x = pk[nb * 2]; wv.y = pk[nb * 2 + 1];
    *reinterpret_cast<uint2*>(pw + (((nb * 32 + lg * 8) ^ sw))) = wv;
  }
  __builtin_amdgcn_s_setprio(1);
#pragma unroll
  for (int kk = 0; kk < 2; ++kk) {
    bf16x8 pa = *reinterpret_cast<const bf16x8*>(pw + ((kk * 64 + lg * 16) ^ sw));
#pragma unroll
    for (int db = 0; db < 4; ++db) {
      int vrow = db * 16 + la;
      bf16x8 vb = *reinterpret_cast<const bf16x8*>(&vt[vrow * 64 + (((kk * 4 + lg) ^ (vrow & 7)) << 3)]);
      o[db] = __builtin_amdgcn_mfma_f32_16x16x32_bf16(pa, vb, o[db], 0, 0, 0);
    }
  }
  __builtin_amdgcn_s_setprio(0);
}

__global__ __launch_bounds__(256, 4) void attn_kernel(const unsigned short* __restrict__ Qh,
                                                      const unsigned short* __restrict__ Kh,
                                                      const unsigned short* __restrict__ Vt,
                                                      unsigned short* __restrict__ outA) {
  __shared__ unsigned short kbuf[2][4096];
  __shared__ unsigned short vbuf[2][4096];
  __shared__ unsigned short plds[4][1024];
  int orig = blockIdx.x;
  int xcd = orig & 7, ix = orig >> 3;
  int bh = xcd * 8 + (ix >> 4);
  int p = ix & 15;
  int qtA = p, qtB = 31 - p;
  int t = threadIdx.x, lane = t & 63, w = t >> 6;
  int la = lane & 15, lg = lane >> 4;
  int kq = w * 16 + la - lg * 4;
  const unsigned short* Qp = Qh + (size_t)bh * SS * DK;
  const unsigned short* Kp = Kh + (size_t)bh * SS * DK;
  const unsigned short* Vtp = Vt + (size_t)bh * DK * SS;
  unsigned short* plw = plds[w];

  int qrA = qtA * 64 + w * 16;
  int qrB = qtB * 64 + w * 16;
  bf16x8 qA0 = *reinterpret_cast<const bf16x8*>(Qp + (size_t)(qrA + la) * 64 + lg * 8);
  bf16x8 qA1 = *reinterpret_cast<const bf16x8*>(Qp + (size_t)(qrA + la) * 64 + 32 + lg * 8);
  bf16x8 qB0 = *reinterpret_cast<const bf16x8*>(Qp + (size_t)(qrB + la) * 64 + lg * 8);
  bf16x8 qB1 = *reinterpret_cast<const bf16x8*>(Qp + (size_t)(qrB + la) * 64 + 32 + lg * 8);

  f32x4 oA[4], oB[4];
#pragma unroll
  for (int i = 0; i < 4; ++i) {
    oA[i] = (f32x4){0.f, 0.f, 0.f, 0.f};
    oB[i] = (f32x4){0.f, 0.f, 0.f, 0.f};
  }
  float mA = -1e30f, lA = 0.f, mB = -1e30f, lB = 0.f;

  int c8 = t & 7, r0 = t >> 3;
  auto stage = [&](int bi, int kv) {
    int kvBase = kv * 64;
#pragma unroll
    for (int i = 0; i < 2; ++i) {
      int r = r0 + i * 32;
      gl_lds16(Kp + (size_t)(kvBase + r) * 64 + ((c8 ^ (r & 7)) << 3),
               &kbuf[bi][t * 8 + i * 2048]);
      gl_lds16(Vtp + (size_t)r * SS + kvBase + ((c8 ^ (r & 7)) << 3),
               &vbuf[bi][t * 8 + i * 2048]);
    }
  };

  stage(0, 0);
  __syncthreads();
  int cur = 0;
  for (int kv = 0; kv <= qtB; ++kv) {
    if (kv < qtB) stage(cur ^ 1, kv + 1);  // prefetch next K/V tile
    bool doA = (kv <= qtA);
    f32x4 stB[4], stA[4];
    __builtin_amdgcn_s_setprio(1);
    qkt_tile(kbuf[cur], la, lg, qB0, qB1, stB);
    if (doA) qkt_tile(kbuf[cur], la, lg, qA0, qA1, stA);
    __builtin_amdgcn_s_setprio(0);
    smpv_tile(stB, vbuf[cur], plw, la, lg, kq, kv == qtB, mB, lB, oB);
    if (doA)
      smpv_tile(stA, vbuf[cur], plw, la, lg, kq, kv == qtA, mA, lA, oA);
    __syncthreads();
    cur ^= 1;
  }

  int b = bh >> 4, h = bh & 15;
#pragma unroll
  for (int j = 0; j < 4; ++j) {
    float ljB = __shfl(lB, lg * 4 + j);
    float ljA = __shfl(lA, lg * 4 + j);
    float riB = 1.0f / ljB, riA = 1.0f / ljA;
    int qB_ = qrB + lg * 4 + j;
    int qA_ = qrA + lg * 4 + j;
#pragma unroll
    for (int db = 0; db < 4; ++db) {
      outA[((size_t)(b * SS + qB_)) * D_MODEL + h * DK + db * 16 + la] = f2b(oB[db][j] * riB);
      outA[((size_t)(b * SS + qA_)) * D_MODEL + h * DK + db * 16 + la] = f2b(oA[db][j] * riA);
    }
  }
}

extern "C" void kernel_launch(void* const* d_in, const int* in_sizes, int n_in,
                              void* d_out, int out_size, void* d_ws, size_t ws_size,
                              hipStream_t stream) {
  (void)in_sizes; (void)n_in; (void)out_size; (void)ws_size;
  const float* x  = (const float*)d_in[0];
  const float* Wq = (const float*)d_in[1];
  const float* Wk = (const float*)d_in[2];
  const float* Wv = (const float*)d_in[3];
  const float* Wo = (const float*)d_in[4];
  const int* pos  = (const int*)d_in[5];

  char* ws = (char*)d_ws;
  unsigned short* xb    = (unsigned short*)(ws);               // 16 MB: x bf16 [8192][1024]
  unsigned short* Wcat  = (unsigned short*)(ws + 16777216);    // 6 MB Wq|Wk|Wv + 2 MB Wo
  unsigned short* Qh    = (unsigned short*)(ws + 25165824);    // Q,K (b,h,s,d); V^T (b,h,d,s)
  unsigned short* attnO = (unsigned short*)(ws + 75497472);    // 16 MB: (b,s,1024) bf16
  float2* ctab          = (float2*)(ws + 92274688);            // 512 KB trig table

  rope_table_kernel<<<256, 256, 0, stream>>>(pos, ctab);
  cast_kernel<<<8192, 256, 0, stream>>>(x, xb, 2097152);
  cast4_kernel<<<4096, 256, 0, stream>>>(Wq, Wk, Wv, Wo, Wcat);

  gemm_bt<1><<<dim3(64, 12), 512, 0, stream>>>(xb, Wcat, Qh, 3072);
  rope_kernel<<<8192, 256, 0, stream>>>(Qh, Qh + 8388608, ctab);
  attn_kernel<<<1024, 256, 0, stream>>>(Qh, Qh + 8388608, Qh + 16777216, attnO);
  gemm_bt<0><<<dim3(64, 4), 512, 0, stream>>>(attnO, Wcat + 3145728, (float*)d_out, 1024);
}

// Round 10
// 202.704 us; speedup vs baseline: 1.3656x; 1.2198x over previous
//
#include <hip/hip_runtime.h>
#include <hip/hip_bf16.h>

#define GAS __attribute__((address_space(1)))
#define LAS __attribute__((address_space(3)))

typedef __attribute__((ext_vector_type(8))) short bf16x8;
typedef __attribute__((ext_vector_type(4))) float f32x4;

#define D_MODEL 1024
#define NHEADS 16
#define DK 64
#define BB 4
#define SS 2048

#define SM_SCALE 0.18033688011112042f  /* 1/sqrt(64) * log2(e), folded into Q at RoPE */

static __device__ __forceinline__ float b2f(unsigned short u) {
  union { unsigned int i; float f; } c; c.i = ((unsigned int)u) << 16; return c.f;
}
static __device__ __forceinline__ unsigned short f2b(float f) {
  union { float f; unsigned int i; } c; c.f = f;
  unsigned int x = c.i;
  x += 0x7fffu + ((x >> 16) & 1u);   // RNE
  return (unsigned short)(x >> 16);
}
// pack 2 f32 -> 2 bf16 (RNE) in one instruction
static __device__ __forceinline__ unsigned int cvtpk(float lo, float hi) {
  unsigned int r;
  asm("v_cvt_pk_bf16_f32 %0, %1, %2" : "=v"(r) : "v"(lo), "v"(hi));
  return r;
}
// raw 2^x (hardware v_exp_f32)
static __device__ __forceinline__ float fexp2(float x) {
  float r;
  asm("v_exp_f32 %0, %1" : "=v"(r) : "v"(x));
  return r;
}

// ---------------- cast f32 -> bf16 (vectorized float4 -> ushort4) ----------
__global__ __launch_bounds__(256) void cast_kernel(const float* __restrict__ in,
                                                   unsigned short* __restrict__ out,
                                                   int n4) {
  int i = blockIdx.x * 256 + threadIdx.x;
  if (i >= n4) return;
  float4 v = reinterpret_cast<const float4*>(in)[i];
  ushort4 o;
  o.x = f2b(v.x); o.y = f2b(v.y); o.z = f2b(v.z); o.w = f2b(v.w);
  reinterpret_cast<ushort4*>(out)[i] = o;
}

// all 4 weight matrices in one launch; dst regions are contiguous in ws
__global__ __launch_bounds__(256) void cast4_kernel(const float* __restrict__ a,
                                                    const float* __restrict__ b,
                                                    const float* __restrict__ c,
                                                    const float* __restrict__ d,
                                                    unsigned short* __restrict__ out) {
  int i = blockIdx.x * 256 + threadIdx.x;  // < 4 * 262144
  int which = i >> 18, off = i & 0x3ffff;
  const float* src = which == 0 ? a : which == 1 ? b : which == 2 ? c : d;
  float4 v = reinterpret_cast<const float4*>(src)[off];
  ushort4 o;
  o.x = f2b(v.x); o.y = f2b(v.y); o.z = f2b(v.z); o.w = f2b(v.w);
  reinterpret_cast<ushort4*>(out)[i] = o;
}

// ---------------- bf16 GEMM v3: C = A (M x K) * B^T (N x K), K = 1024 ------
// 128x256 tile, BK=64, 512 threads = 8 waves (2M x 4N), 64x64 per wave.
// SINGLE-buffered LDS (48 KB -> 3 blocks/CU, 24 waves/CU; cross-block
// overlap hides stage drain per m114). Chunk-XOR swizzle (pre-swizzled
// global_load_lds source + same XOR on ds_read_b128 -> 0 conflicts, R9).
// XCD partition: block b -> bx=(b&7)*8+((b>>3)&7), by=b>>6; each XCD owns
// 8 A-panels (2 MB, L2-resident) and streams B panels.
static __device__ __forceinline__ void gl_lds16(const void* g, void* l) {
  __builtin_amdgcn_global_load_lds((const GAS unsigned int*)g,
                                   (LAS unsigned int*)l, 16, 0, 0);
}

template <int EPI>
__global__ __launch_bounds__(512, 2) void gemm_bt(const unsigned short* __restrict__ A,
                                                  const unsigned short* __restrict__ Bw,
                                                  void* __restrict__ outp, int N) {
  const int K = 1024;
  const int NT = 16;  // K / 64
  __shared__ unsigned short lds_a[128 * 64];
  __shared__ unsigned short lds_b[256 * 64];
  int t = threadIdx.x;
  int lane = t & 63;
  int w = t >> 6, wr = w >> 2, wc = w & 3;  // 2 x 4 wave grid
  int la = lane & 15, lg = lane >> 4;
  // XCD-aware 2D partition (blocks round-robin XCDs by id & 7)
  int b = blockIdx.x;
  int bx = ((b & 7) << 3) | ((b >> 3) & 7);
  int by = b >> 6;
  int rowBase = bx * 128;
  int colBase = by * 256;

  int c8 = t & 7, r0 = t >> 3;  // staging: row r0 (+64/round), 16B chunk c8
  const unsigned short* Abase = A + (size_t)rowBase * K;
  const unsigned short* Bbase = Bw + (size_t)colBase * K;
  // LDS row-major [rows][64]; slot (r=r0+i*64, c8) -> element t*8 + i*4096.
  auto stage = [&](int kt) {
    int k0 = kt * 64;
#pragma unroll
    for (int i = 0; i < 2; ++i) {
      int r = r0 + i * 64;
      gl_lds16(Abase + (size_t)r * K + k0 + ((c8 ^ (r & 7)) << 3),
               &lds_a[t * 8 + i * 4096]);
    }
#pragma unroll
    for (int i = 0; i < 4; ++i) {
      int r = r0 + i * 64;
      gl_lds16(Bbase + (size_t)r * K + k0 + ((c8 ^ (r & 7)) << 3),
               &lds_b[t * 8 + i * 4096]);
    }
  };

  f32x4 acc[4][4];
#pragma unroll
  for (int i = 0; i < 4; ++i)
#pragma unroll
    for (int j = 0; j < 4; ++j) acc[i][j] = (f32x4){0.f, 0.f, 0.f, 0.f};

  for (int kt = 0; kt < NT; ++kt) {
    __syncthreads();  // all waves done reading lds from previous tile
    stage(kt);
    __syncthreads();  // staging complete (compiler drains vmcnt before barrier)
#pragma unroll
    for (int s = 0; s < 2; ++s) {
      bf16x8 af[4], bfr[4];
#pragma unroll
      for (int mi = 0; mi < 4; ++mi) {
        int row = wr * 64 + mi * 16 + la;
        af[mi] = *reinterpret_cast<const bf16x8*>(
            &lds_a[row * 64 + (((s * 4 + lg) ^ (row & 7)) << 3)]);
      }
#pragma unroll
      for (int ni = 0; ni < 4; ++ni) {
        int row = wc * 64 + ni * 16 + la;
        bfr[ni] = *reinterpret_cast<const bf16x8*>(
            &lds_b[row * 64 + (((s * 4 + lg) ^ (row & 7)) << 3)]);
      }
      __builtin_amdgcn_s_setprio(1);
#pragma unroll
      for (int mi = 0; mi < 4; ++mi)
#pragma unroll
        for (int ni = 0; ni < 4; ++ni)
          acc[mi][ni] = __builtin_amdgcn_mfma_f32_16x16x32_bf16(af[mi], bfr[ni],
                                                                acc[mi][ni], 0, 0, 0);
      __builtin_amdgcn_s_setprio(0);
    }
  }

  if (EPI == 0) {
    float* out = (float*)outp;
#pragma unroll
    for (int mi = 0; mi < 4; ++mi)
#pragma unroll
      for (int ni = 0; ni < 4; ++ni)
#pragma unroll
        for (int j = 0; j < 4; ++j) {
          int row = rowBase + wr * 64 + mi * 16 + lg * 4 + j;
          int col = colBase + wc * 64 + ni * 16 + la;
          out[(size_t)row * N + col] = acc[mi][ni][j];
        }
  } else {
    // Q,K: [which][b,h,s,d].  V: transposed [b,h,d,s].
    unsigned short* qkv = (unsigned short*)outp;
#pragma unroll
    for (int mi = 0; mi < 4; ++mi)
#pragma unroll
      for (int ni = 0; ni < 4; ++ni)
#pragma unroll
        for (int j = 0; j < 4; ++j) {
          int row = rowBase + wr * 64 + mi * 16 + lg * 4 + j;
          int col = colBase + wc * 64 + ni * 16 + la;
          int which = col >> 10, d = col & 1023;
          int h = d >> 6, dd = d & 63;
          int bb = row >> 11, s = row & 2047;
          size_t off;
          if (which == 2)
            off = (size_t)2 * 8388608 +
                  ((size_t)(bb * NHEADS + h) * DK + dd) * SS + s;
          else
            off = (size_t)which * 8388608 +
                  ((size_t)(bb * NHEADS + h) * SS + s) * DK + dd;
          qkv[off] = f2b(acc[mi][ni][j]);
        }
  }
}

// ---------------- RoPE: trig table + vectorized apply ----------------------
__global__ __launch_bounds__(256) void rope_table_kernel(const int* __restrict__ pos,
                                                         float2* __restrict__ ctab) {
  int i = blockIdx.x * 256 + threadIdx.x;  // 2048 * 32
  int s = i >> 5, pr = i & 31;
  float p = (float)pos[s];
  float ang = p * __expf(-(float)pr * 0.2878231366242557f);  // ln(1e4)/32
  float sn, cs;
  sincosf(ang, &sn, &cs);
  ctab[i] = make_float2(cs, sn);
}

// each thread: 4 pairs (16B). Q rows scaled by SM_SCALE.
__global__ __launch_bounds__(256) void rope_kernel(unsigned short* __restrict__ Q,
                                                   unsigned short* __restrict__ Kk,
                                                   const float2* __restrict__ ctab) {
  int i = blockIdx.x * 256 + threadIdx.x;  // < 2 * 64*2048*8 = 2097152
  int seg = i & 7;
  int row = (i >> 3) & 131071;  // bh*2048 + s
  int isK = i >> 20;
  unsigned short* base = isK ? Kk : Q;
  int s = row & 2047;
  float sc = isK ? 1.0f : SM_SCALE;
  const float4* ct4 = reinterpret_cast<const float4*>(ctab + s * 32 + seg * 4);
  float4 ca = ct4[0], cb = ct4[1];  // (c0,s0,c1,s1), (c2,s2,c3,s3)
  unsigned int* pp = reinterpret_cast<unsigned int*>(base + (size_t)row * 64 + seg * 8);
  uint4 v = *reinterpret_cast<uint4*>(pp);
  uint4 r;
  {
    float x1 = b2f((unsigned short)(v.x & 0xffffu)), x2 = b2f((unsigned short)(v.x >> 16));
    r.x = cvtpk((x1 * ca.x - x2 * ca.y) * sc, (x1 * ca.y + x2 * ca.x) * sc);
    x1 = b2f((unsigned short)(v.y & 0xffffu)); x2 = b2f((unsigned short)(v.y >> 16));
    r.y = cvtpk((x1 * ca.z - x2 * ca.w) * sc, (x1 * ca.w + x2 * ca.z) * sc);
    x1 = b2f((unsigned short)(v.z & 0xffffu)); x2 = b2f((unsigned short)(v.z >> 16));
    r.z = cvtpk((x1 * cb.x - x2 * cb.y) * sc, (x1 * cb.y + x2 * cb.x) * sc);
    x1 = b2f((unsigned short)(v.w & 0xffffu)); x2 = b2f((unsigned short)(v.w >> 16));
    r.w = cvtpk((x1 * cb.z - x2 * cb.w) * sc, (x1 * cb.w + x2 * cb.z) * sc);
  }
  *reinterpret_cast<uint4*>(pp) = r;
}

// ---------------- flash attention v5 (unchanged from R7/R9) ----------------
static __device__ __forceinline__ void qkt_tile(
    const unsigned short* __restrict__ kt, int la, int lg,
    bf16x8 q0, bf16x8 q1, f32x4* st) {
#pragma unroll
  for (int nb = 0; nb < 4; ++nb) {
    int krow = nb * 16 + la;
    bf16x8 k0 = *reinterpret_cast<const bf16x8*>(&kt[krow * 64 + ((lg ^ (krow & 7)) << 3)]);
    bf16x8 k1 = *reinterpret_cast<const bf16x8*>(&kt[krow * 64 + (((4 + lg) ^ (krow & 7)) << 3)]);
    f32x4 s = (f32x4){0.f, 0.f, 0.f, 0.f};
    s = __builtin_amdgcn_mfma_f32_16x16x32_bf16(k0, q0, s, 0, 0, 0);
    s = __builtin_amdgcn_mfma_f32_16x16x32_bf16(k1, q1, s, 0, 0, 0);
    st[nb] = s;
  }
}

static __device__ __forceinline__ void smpv_tile(
    const f32x4* __restrict__ st, const unsigned short* __restrict__ vt,
    unsigned short* __restrict__ pl, int la, int lg, int kq, bool diag,
    float& m, float& l, f32x4* o) {
  float sv[16];
#pragma unroll
  for (int nb = 0; nb < 4; ++nb)
#pragma unroll
    for (int j = 0; j < 4; ++j) {
      float v = st[nb][j];
      if (diag && (nb * 16 + j) > kq) v = -1e30f;  // key_in > q_in
      sv[nb * 4 + j] = v;
    }
  float t1 = fmaxf(fmaxf(sv[0], sv[1]), sv[2]);
  float t2 = fmaxf(fmaxf(sv[3], sv[4]), sv[5]);
  float t3 = fmaxf(fmaxf(sv[6], sv[7]), sv[8]);
  float t4 = fmaxf(fmaxf(sv[9], sv[10]), sv[11]);
  float t5 = fmaxf(fmaxf(sv[12], sv[13]), sv[14]);
  float tm = fmaxf(fmaxf(fmaxf(t1, t2), t3), fmaxf(fmaxf(t4, t5), sv[15]));
  tm = fmaxf(tm, __shfl_xor(tm, 16));
  tm = fmaxf(tm, __shfl_xor(tm, 32));
  if (!__all(tm <= m + 8.0f)) {
    float mnew = fmaxf(m, tm);
    float corr = fexp2(m - mnew);
    m = mnew;
    l *= corr;
#pragma unroll
    for (int j = 0; j < 4; ++j) {
      float cj = __shfl(corr, lg * 4 + j);
#pragma unroll
      for (int db = 0; db < 4; ++db) o[db][j] *= cj;
    }
  }
  float rs0 = 0.f, rs1 = 0.f;
  unsigned int pk[8];
#pragma unroll
  for (int i = 0; i < 8; ++i) {
    float p0 = fexp2(sv[2 * i] - m);
    float p1 = fexp2(sv[2 * i + 1] - m);
    rs0 += p0; rs1 += p1;
    pk[i] = cvtpk(p0, p1);
  }
  float rs = rs0 + rs1;
  rs += __shfl_xor(rs, 16);
  rs += __shfl_xor(rs, 32);
  l += rs;
  char* pw = (char*)pl + la * 128;
  int sw = (la & 7) << 4;
#pragma unroll
  for (int nb = 0; nb < 4; ++nb) {
    uint2 wv; wv.x = pk[nb * 2]; wv.y = pk[nb * 2 + 1];
    *reinterpret_cast<uint2*>(pw + (((nb * 32 + lg * 8) ^ sw))) = wv;
  }
  __builtin_amdgcn_s_setprio(1);
#pragma unroll
  for (int kk = 0; kk < 2; ++kk) {
    bf16x8 pa = *reinterpret_cast<const bf16x8*>(pw + ((kk * 64 + lg * 16) ^ sw));
#pragma unroll
    for (int db = 0; db < 4; ++db) {
      int vrow = db * 16 + la;
      bf16x8 vb = *reinterpret_cast<const bf16x8*>(&vt[vrow * 64 + (((kk * 4 + lg) ^ (vrow & 7)) << 3)]);
      o[db] = __builtin_amdgcn_mfma_f32_16x16x32_bf16(pa, vb, o[db], 0, 0, 0);
    }
  }
  __builtin_amdgcn_s_setprio(0);
}

__global__ __launch_bounds__(256, 4) void attn_kernel(const unsigned short* __restrict__ Qh,
                                                      const unsigned short* __restrict__ Kh,
                                                      const unsigned short* __restrict__ Vt,
                                                      unsigned short* __restrict__ outA) {
  __shared__ unsigned short kbuf[2][4096];
  __shared__ unsigned short vbuf[2][4096];
  __shared__ unsigned short plds[4][1024];
  int orig = blockIdx.x;
  int xcd = orig & 7, ix = orig >> 3;
  int bh = xcd * 8 + (ix >> 4);
  int p = ix & 15;
  int qtA = p, qtB = 31 - p;
  int t = threadIdx.x, lane = t & 63, w = t >> 6;
  int la = lane & 15, lg = lane >> 4;
  int kq = w * 16 + la - lg * 4;
  const unsigned short* Qp = Qh + (size_t)bh * SS * DK;
  const unsigned short* Kp = Kh + (size_t)bh * SS * DK;
  const unsigned short* Vtp = Vt + (size_t)bh * DK * SS;
  unsigned short* plw = plds[w];

  int qrA = qtA * 64 + w * 16;
  int qrB = qtB * 64 + w * 16;
  bf16x8 qA0 = *reinterpret_cast<const bf16x8*>(Qp + (size_t)(qrA + la) * 64 + lg * 8);
  bf16x8 qA1 = *reinterpret_cast<const bf16x8*>(Qp + (size_t)(qrA + la) * 64 + 32 + lg * 8);
  bf16x8 qB0 = *reinterpret_cast<const bf16x8*>(Qp + (size_t)(qrB + la) * 64 + lg * 8);
  bf16x8 qB1 = *reinterpret_cast<const bf16x8*>(Qp + (size_t)(qrB + la) * 64 + 32 + lg * 8);

  f32x4 oA[4], oB[4];
#pragma unroll
  for (int i = 0; i < 4; ++i) {
    oA[i] = (f32x4){0.f, 0.f, 0.f, 0.f};
    oB[i] = (f32x4){0.f, 0.f, 0.f, 0.f};
  }
  float mA = -1e30f, lA = 0.f, mB = -1e30f, lB = 0.f;

  int c8 = t & 7, r0 = t >> 3;
  auto stage = [&](int bi, int kv) {
    int kvBase = kv * 64;
#pragma unroll
    for (int i = 0; i < 2; ++i) {
      int r = r0 + i * 32;
      gl_lds16(Kp + (size_t)(kvBase + r) * 64 + ((c8 ^ (r & 7)) << 3),
               &kbuf[bi][t * 8 + i * 2048]);
      gl_lds16(Vtp + (size_t)r * SS + kvBase + ((c8 ^ (r & 7)) << 3),
               &vbuf[bi][t * 8 + i * 2048]);
    }
  };

  stage(0, 0);
  __syncthreads();
  int cur = 0;
  for (int kv = 0; kv <= qtB; ++kv) {
    if (kv < qtB) stage(cur ^ 1, kv + 1);  // prefetch next K/V tile
    bool doA = (kv <= qtA);
    f32x4 stB[4], stA[4];
    __builtin_amdgcn_s_setprio(1);
    qkt_tile(kbuf[cur], la, lg, qB0, qB1, stB);
    if (doA) qkt_tile(kbuf[cur], la, lg, qA0, qA1, stA);
    __builtin_amdgcn_s_setprio(0);
    smpv_tile(stB, vbuf[cur], plw, la, lg, kq, kv == qtB, mB, lB, oB);
    if (doA)
      smpv_tile(stA, vbuf[cur], plw, la, lg, kq, kv == qtA, mA, lA, oA);
    __syncthreads();
    cur ^= 1;
  }

  int b = bh >> 4, h = bh & 15;
#pragma unroll
  for (int j = 0; j < 4; ++j) {
    float ljB = __shfl(lB, lg * 4 + j);
    float ljA = __shfl(lA, lg * 4 + j);
    float riB = 1.0f / ljB, riA = 1.0f / ljA;
    int qB_ = qrB + lg * 4 + j;
    int qA_ = qrA + lg * 4 + j;
#pragma unroll
    for (int db = 0; db < 4; ++db) {
      outA[((size_t)(b * SS + qB_)) * D_MODEL + h * DK + db * 16 + la] = f2b(oB[db][j] * riB);
      outA[((size_t)(b * SS + qA_)) * D_MODEL + h * DK + db * 16 + la] = f2b(oA[db][j] * riA);
    }
  }
}

extern "C" void kernel_launch(void* const* d_in, const int* in_sizes, int n_in,
                              void* d_out, int out_size, void* d_ws, size_t ws_size,
                              hipStream_t stream) {
  (void)in_sizes; (void)n_in; (void)out_size; (void)ws_size;
  const float* x  = (const float*)d_in[0];
  const float* Wq = (const float*)d_in[1];
  const float* Wk = (const float*)d_in[2];
  const float* Wv = (const float*)d_in[3];
  const float* Wo = (const float*)d_in[4];
  const int* pos  = (const int*)d_in[5];

  char* ws = (char*)d_ws;
  unsigned short* xb    = (unsigned short*)(ws);               // 16 MB: x bf16 [8192][1024]
  unsigned short* Wcat  = (unsigned short*)(ws + 16777216);    // 6 MB Wq|Wk|Wv + 2 MB Wo
  unsigned short* Qh    = (unsigned short*)(ws + 25165824);    // Q,K (b,h,s,d); V^T (b,h,d,s)
  unsigned short* attnO = (unsigned short*)(ws + 75497472);    // 16 MB: (b,s,1024) bf16
  float2* ctab          = (float2*)(ws + 92274688);            // 512 KB trig table

  rope_table_kernel<<<256, 256, 0, stream>>>(pos, ctab);
  cast_kernel<<<8192, 256, 0, stream>>>(x, xb, 2097152);
  cast4_kernel<<<4096, 256, 0, stream>>>(Wq, Wk, Wv, Wo, Wcat);

  gemm_bt<1><<<768, 512, 0, stream>>>(xb, Wcat, Qh, 3072);
  rope_kernel<<<8192, 256, 0, stream>>>(Qh, Qh + 8388608, ctab);
  attn_kernel<<<1024, 256, 0, stream>>>(Qh, Qh + 8388608, Qh + 16777216, attnO);
  gemm_bt<0><<<256, 512, 0, stream>>>(attnO, Wcat + 3145728, (float*)d_out, 1024);
}